// Round 3
// baseline (698.052 us; speedup 1.0000x reference)
//
#include <hip/hip_runtime.h>
#include <stdint.h>

#define Hh 8
#define Bb 32
#define Tt 512
#define Ee 512
#define Nn 16384            // Bb*Tt
#define GAMMA_ 1.5f
#define BN_EPS_ 1e-5f

typedef _Float16 f16x4 __attribute__((ext_vector_type(4)));
typedef _Float16 f16x8 __attribute__((ext_vector_type(8)));
typedef float    f32x4 __attribute__((ext_vector_type(4)));

__device__ __forceinline__ void async_ld16(void* lds, const void* g) {
    __builtin_amdgcn_global_load_lds(
        (const __attribute__((address_space(1))) void*)g,
        (__attribute__((address_space(3))) void*)lds, 16, 0, 0);
}

// Full-wave (64-lane) f32 sum via DPP (pure VALU, no DS pipe).
__device__ __forceinline__ float dpp_sum64(float v) {
    int t;
    t = __builtin_amdgcn_update_dpp(0, __float_as_int(v), 0x111, 0xf, 0xf, true);
    v += __int_as_float(t);
    t = __builtin_amdgcn_update_dpp(0, __float_as_int(v), 0x112, 0xf, 0xf, true);
    v += __int_as_float(t);
    t = __builtin_amdgcn_update_dpp(0, __float_as_int(v), 0x114, 0xf, 0xf, true);
    v += __int_as_float(t);
    t = __builtin_amdgcn_update_dpp(0, __float_as_int(v), 0x118, 0xf, 0xf, true);
    v += __int_as_float(t);
    t = __builtin_amdgcn_update_dpp(0, __float_as_int(v), 0x142, 0xf, 0xf, true);
    v += __int_as_float(t);
    t = __builtin_amdgcn_update_dpp(0, __float_as_int(v), 0x143, 0xf, 0xf, true);
    v += __int_as_float(t);
    return __int_as_float(__builtin_amdgcn_readlane(__float_as_int(v), 63));
}

// ---------------- K0: fp32 -> f16 convert (x then W, contiguous) ----------------
__global__ __launch_bounds__(256) void cvt_kernel(const float* __restrict__ x,
                                                  const float* __restrict__ W,
                                                  _Float16* __restrict__ xh,
                                                  _Float16* __restrict__ wh) {
    const int NX = Bb * Tt * Ee;               // 8388608, divisible by 4
    int i = (blockIdx.x * 256 + threadIdx.x) * 4;
    if (i < NX) {
        float4 v = *(const float4*)(x + i);
        f16x4 o = {(_Float16)v.x, (_Float16)v.y, (_Float16)v.z, (_Float16)v.w};
        *(f16x4*)(xh + i) = o;
    } else {
        int j = i - NX;                        // 0 .. 2097151
        float4 v = *(const float4*)(W + j);
        f16x4 o = {(_Float16)v.x, (_Float16)v.y, (_Float16)v.z, (_Float16)v.w};
        *(f16x4*)(wh + j) = o;
    }
}

// ---------------- K1: batched NT GEMM, f16 MFMA, double-buffered LDS ------------
// 1D grid 4096, XCD-aware swizzle: 32 consecutive blocks = 8mb x 4nb at one h;
// same-XCD subsets (id%8 equal) form 2x2 tiles sharing A and B in L2.
__global__ __launch_bounds__(256) void gemm_kernel(const _Float16* __restrict__ A,
                                                   const _Float16* __restrict__ Bm,
                                                   _Float16* __restrict__ C,
                                                   float* __restrict__ sums,
                                                   float* __restrict__ sumsq) {
    __shared__ alignas(16) _Float16 As[2][128 * 32];   // 2 x 8 KB
    __shared__ alignas(16) _Float16 Bs[2][128 * 32];   // 2 x 8 KB
    const int id = blockIdx.x;                 // 0..4095
    const int g  = id >> 5;                    // 128 groups
    const int r  = id & 31;
    const int h  = g >> 4;                     // 8
    const int q  = r & 7;                      // XCD slot (heuristic)
    const int s  = r >> 3;
    const int mb = ((g & 15) * 8 + (q & 3) * 2 + (s & 1)) * 128;
    const int nb = ((q >> 2) * 2 + (s >> 1)) * 128;

    const int t    = threadIdx.x;
    const int lane = t & 63;
    const int w    = t >> 6;
    const int wm   = (w >> 1) * 64;
    const int wn   = (w & 1) * 64;
    const int quad = lane >> 4;
    const int l16  = lane & 15;

    // staging: thread t loads 16B chunks c=t and c=t+256; row=c>>2, k-off=(c&3)*8
    const _Float16* Ap = A + (size_t)(mb + (t >> 2)) * Ee + (t & 3) * 8;
    const _Float16* Bp = Bm + (size_t)h * Ee * Ee + (size_t)(nb + (t >> 2)) * Ee + (t & 3) * 8;

    f32x4 acc[4][4] = {};

    // prologue: stage k0=0 into buf 0
    async_ld16(&As[0][t * 8],        Ap);
    async_ld16(&As[0][2048 + t * 8], Ap + 64 * Ee);
    async_ld16(&Bs[0][t * 8],        Bp);
    async_ld16(&Bs[0][2048 + t * 8], Bp + 64 * Ee);

    int buf = 0;
    for (int k0 = 0; k0 < Ee; k0 += 32) {
        __syncthreads();   // drains loads for `buf`; also closes reads of buf^1
        if (k0 + 32 < Ee) {
            int nb2 = buf ^ 1;
            async_ld16(&As[nb2][t * 8],        Ap + k0 + 32);
            async_ld16(&As[nb2][2048 + t * 8], Ap + 64 * Ee + k0 + 32);
            async_ld16(&Bs[nb2][t * 8],        Bp + k0 + 32);
            async_ld16(&Bs[nb2][2048 + t * 8], Bp + 64 * Ee + k0 + 32);
        }
        f16x8 a8[4], b8[4];
#pragma unroll
        for (int mt = 0; mt < 4; ++mt)
            a8[mt] = *(const f16x8*)(&As[buf][(wm + mt * 16 + l16) * 32 + quad * 8]);
#pragma unroll
        for (int nt = 0; nt < 4; ++nt)
            b8[nt] = *(const f16x8*)(&Bs[buf][(wn + nt * 16 + l16) * 32 + quad * 8]);
#pragma unroll
        for (int mt = 0; mt < 4; ++mt)
#pragma unroll
            for (int nt = 0; nt < 4; ++nt)
                acc[mt][nt] = __builtin_amdgcn_mfma_f32_16x16x32_f16(a8[mt], b8[nt], acc[mt][nt], 0, 0, 0);
        buf ^= 1;
    }

    // BN partial sums: reduce over rows (mt,r) then across quads (lanes xor 16,32)
#pragma unroll
    for (int nt = 0; nt < 4; ++nt) {
        float sv = 0.f, ss = 0.f;
#pragma unroll
        for (int mt = 0; mt < 4; ++mt)
#pragma unroll
            for (int rr = 0; rr < 4; ++rr) { float v = acc[mt][nt][rr]; sv += v; ss += v * v; }
        sv += __shfl_xor(sv, 16, 64); sv += __shfl_xor(sv, 32, 64);
        ss += __shfl_xor(ss, 16, 64); ss += __shfl_xor(ss, 32, 64);
        if (quad == 0) {
            int col = nb + wn + nt * 16 + l16;
            atomicAdd(&sums[h * Ee + col], sv);
            atomicAdd(&sumsq[h * Ee + col], ss);
        }
    }

    // store C (f16): C/D layout col=lane&15, row=quad*4+reg
    _Float16* Cp = C + (size_t)h * Nn * Ee;
#pragma unroll
    for (int mt = 0; mt < 4; ++mt)
#pragma unroll
        for (int rr = 0; rr < 4; ++rr) {
            int row = mb + wm + mt * 16 + quad * 4 + rr;
            size_t off = (size_t)row * Ee + nb + wn + l16;
#pragma unroll
            for (int nt = 0; nt < 4; ++nt)
                Cp[off + nt * 16] = (_Float16)acc[mt][nt][rr];
        }
}

// ---------------- K2: finalize BN stats into affine coefs -----------------------
__global__ __launch_bounds__(256) void stats_kernel(const float* __restrict__ sums,
                                                    const float* __restrict__ sumsq,
                                                    const float* __restrict__ bnw,
                                                    const float* __restrict__ bnb,
                                                    float* __restrict__ cA,
                                                    float* __restrict__ cB) {
    int i = blockIdx.x * 256 + threadIdx.x;    // 0..4095
    float mean = sums[i] * (1.0f / Nn);
    float var  = sumsq[i] * (1.0f / Nn) - mean * mean;
    float inv  = rsqrtf(var + BN_EPS_);
    float a    = bnw[i] * inv;
    cA[i] = a;
    cB[i] = bnb[i] - mean * a;
}

// ---------------- K3: per-row head scan: sparsemax (Michelot, DPP) --------------
// 256 threads = 4 waves, each wave owns one row n. Lane holds elems
// [lane*4, lane*4+4) and [256+lane*4, +4). h-loop kept ROLLED (register economy).
__global__ __launch_bounds__(256) void rows_kernel(const float* __restrict__ x,
                                                   const _Float16* __restrict__ lg,
                                                   const float* __restrict__ cA,
                                                   const float* __restrict__ cB,
                                                   float* __restrict__ out) {
    const int n    = blockIdx.x * 4 + (threadIdx.x >> 6);
    const int lane = threadIdx.x & 63;
    const int e0   = lane * 4;                 // first chunk; second at +256
    const int bb   = n >> 9;                   // n / Tt
    const int tt   = n & 511;                  // n % Tt

    float xr[8], prior[8];
    {
        const float* xp = x + (size_t)n * Ee;
        float4 x0 = *(const float4*)(xp + e0);
        float4 x1 = *(const float4*)(xp + 256 + e0);
        xr[0]=x0.x; xr[1]=x0.y; xr[2]=x0.z; xr[3]=x0.w;
        xr[4]=x1.x; xr[5]=x1.y; xr[6]=x1.z; xr[7]=x1.w;
    }
#pragma unroll
    for (int j = 0; j < 8; ++j) prior[j] = 1.0f;

    float* omx = out;                               // (H,B,T,E) flat = (H,N,E)
    float* omk = out + (size_t)Hh * Nn * Ee;        // (B,H,T,E)

    const _Float16* lrow = lg + (size_t)n * Ee;
    f16x4 l0 = *(const f16x4*)(lrow + e0);
    f16x4 l1 = *(const f16x4*)(lrow + 256 + e0);

#pragma unroll 1
    for (int h = 0; h < Hh; ++h) {
        // depth-1 prefetch of next head's logits (independent of prior chain)
        f16x4 p0 = l0, p1 = l1;
        if (h + 1 < Hh) {
            const _Float16* lnx = lrow + (size_t)(h + 1) * Nn * Ee;
            p0 = *(const f16x4*)(lnx + e0);
            p1 = *(const f16x4*)(lnx + 256 + e0);
        }
        float z[8];
        {
            const float* ap = cA + h * Ee + e0;
            const float* bp = cB + h * Ee + e0;
            float4 a0 = *(const float4*)(ap);
            float4 b0 = *(const float4*)(bp);
            float4 a1 = *(const float4*)(ap + 256);
            float4 b1 = *(const float4*)(bp + 256);
            z[0] = ((float)l0[0] * a0.x + b0.x) * prior[0];
            z[1] = ((float)l0[1] * a0.y + b0.y) * prior[1];
            z[2] = ((float)l0[2] * a0.z + b0.z) * prior[2];
            z[3] = ((float)l0[3] * a0.w + b0.w) * prior[3];
            z[4] = ((float)l1[0] * a1.x + b1.x) * prior[4];
            z[5] = ((float)l1[1] * a1.y + b1.y) * prior[5];
            z[6] = ((float)l1[2] * a1.z + b1.z) * prior[6];
            z[7] = ((float)l1[3] * a1.w + b1.w) * prior[7];
        }

        // Michelot (exact sparsemax threshold), DPP wave reductions.
        float sl = 0.f;
#pragma unroll
        for (int j = 0; j < 8; ++j) sl += z[j];
        float tau = (dpp_sum64(sl) - 1.0f) * (1.0f / 512.0f);
        int cprev = 512;
#pragma unroll 1
        for (int it = 0; it < 64; ++it) {
            float s2 = 0.f, cf = 0.f;
#pragma unroll
            for (int j = 0; j < 8; ++j) {
                bool p = z[j] > tau;
                s2 += p ? z[j] : 0.0f;
                cf += p ? 1.0f : 0.0f;
            }
            float S  = dpp_sum64(s2);
            float Cc = dpp_sum64(cf);
            int c = (int)Cc;
            if (c == cprev) break;
            cprev = c;
            tau = (S - 1.0f) / Cc;
        }

        size_t oxoff = ((size_t)h * Nn + n) * Ee + e0;
        size_t okoff = (((size_t)bb * Hh + h) * Tt + tt) * Ee + e0;
        f32x4 vx, vm;
#pragma unroll
        for (int j = 0; j < 4; ++j) {
            float m = fmaxf(z[j] - tau, 0.0f);
            prior[j] *= fmaxf(GAMMA_ - m, 0.0f);
            vm[j] = m; vx[j] = xr[j] * m;
        }
        __builtin_nontemporal_store(vx, (f32x4*)(omx + oxoff));
        __builtin_nontemporal_store(vm, (f32x4*)(omk + okoff));
#pragma unroll
        for (int j = 0; j < 4; ++j) {
            float m = fmaxf(z[4 + j] - tau, 0.0f);
            prior[4 + j] *= fmaxf(GAMMA_ - m, 0.0f);
            vm[j] = m; vx[j] = xr[4 + j] * m;
        }
        __builtin_nontemporal_store(vx, (f32x4*)(omx + oxoff + 256));
        __builtin_nontemporal_store(vm, (f32x4*)(omk + okoff + 256));
        l0 = p0; l1 = p1;
    }
}

extern "C" void kernel_launch(void* const* d_in, const int* in_sizes, int n_in,
                              void* d_out, int out_size, void* d_ws, size_t ws_size,
                              hipStream_t stream) {
    const float* x   = (const float*)d_in[0];
    const float* W   = (const float*)d_in[1];
    const float* bnw = (const float*)d_in[2];
    const float* bnb = (const float*)d_in[3];
    float* out = (float*)d_out;

    uint8_t* ws = (uint8_t*)d_ws;
    _Float16* xh = (_Float16*)(ws);                    // 16,777,216 B
    _Float16* wh = (_Float16*)(ws + 16777216);         //  4,194,304 B
    _Float16* lg = (_Float16*)(ws + 20971520);         // 134,217,728 B
    float* sums  = (float*)(ws + 155189248);           // 16,384 B
    float* sumsq = (float*)(ws + 155205632);           // 16,384 B
    float* cA    = (float*)(ws + 155222016);           // 16,384 B
    float* cB    = (float*)(ws + 155238400);           // 16,384 B (total ~148 MB)

    hipMemsetAsync(sums, 0, 2 * 4096 * sizeof(float), stream);  // sums+sumsq contiguous

    cvt_kernel<<<10240, 256, 0, stream>>>(x, W, xh, wh);
    gemm_kernel<<<4096, 256, 0, stream>>>(xh, wh, lg, sums, sumsq);
    stats_kernel<<<16, 256, 0, stream>>>(sums, sumsq, bnw, bnb, cA, cB);
    rows_kernel<<<4096, 256, 0, stream>>>(x, lg, cA, cB, out);
}

// Round 4
// 671.797 us; speedup vs baseline: 1.0391x; 1.0391x over previous
//
#include <hip/hip_runtime.h>
#include <stdint.h>

#define Hh 8
#define Bb 32
#define Tt 512
#define Ee 512
#define Nn 16384            // Bb*Tt
#define GAMMA_ 1.5f
#define BN_EPS_ 1e-5f

typedef _Float16 f16x4 __attribute__((ext_vector_type(4)));
typedef _Float16 f16x8 __attribute__((ext_vector_type(8)));
typedef float    f32x4 __attribute__((ext_vector_type(4)));

__device__ __forceinline__ void async_ld16(void* lds, const void* g) {
    __builtin_amdgcn_global_load_lds(
        (const __attribute__((address_space(1))) void*)g,
        (__attribute__((address_space(3))) void*)lds, 16, 0, 0);
}

// Full-wave (64-lane) f32 sum via DPP (pure VALU, no DS pipe).
__device__ __forceinline__ float dpp_sum64(float v) {
    int t;
    t = __builtin_amdgcn_update_dpp(0, __float_as_int(v), 0x111, 0xf, 0xf, true);
    v += __int_as_float(t);
    t = __builtin_amdgcn_update_dpp(0, __float_as_int(v), 0x112, 0xf, 0xf, true);
    v += __int_as_float(t);
    t = __builtin_amdgcn_update_dpp(0, __float_as_int(v), 0x114, 0xf, 0xf, true);
    v += __int_as_float(t);
    t = __builtin_amdgcn_update_dpp(0, __float_as_int(v), 0x118, 0xf, 0xf, true);
    v += __int_as_float(t);
    t = __builtin_amdgcn_update_dpp(0, __float_as_int(v), 0x142, 0xf, 0xf, true);
    v += __int_as_float(t);
    t = __builtin_amdgcn_update_dpp(0, __float_as_int(v), 0x143, 0xf, 0xf, true);
    v += __int_as_float(t);
    return __int_as_float(__builtin_amdgcn_readlane(__float_as_int(v), 63));
}

// ---------------- K0: fp32 -> f16 convert (x then W, contiguous) ----------------
__global__ __launch_bounds__(256) void cvt_kernel(const float* __restrict__ x,
                                                  const float* __restrict__ W,
                                                  _Float16* __restrict__ xh,
                                                  _Float16* __restrict__ wh) {
    const int NX = Bb * Tt * Ee;               // 8388608, divisible by 4
    int i = (blockIdx.x * 256 + threadIdx.x) * 4;
    if (i < NX) {
        float4 v = *(const float4*)(x + i);
        f16x4 o = {(_Float16)v.x, (_Float16)v.y, (_Float16)v.z, (_Float16)v.w};
        *(f16x4*)(xh + i) = o;
    } else {
        int j = i - NX;                        // 0 .. 2097151
        float4 v = *(const float4*)(W + j);
        f16x4 o = {(_Float16)v.x, (_Float16)v.y, (_Float16)v.z, (_Float16)v.w};
        *(f16x4*)(wh + j) = o;
    }
}

// ---------------- K1: batched NT GEMM, f16 MFMA, double-buffered LDS ------------
// K-chunk XOR/rotate swizzle: LDS slot (row r, s) holds global chunk (s-(r>>1))&3
// -> wave64 ds_read_b128 hits the 2-lanes/bank minimum (bank-conflict-free).
__global__ __launch_bounds__(256) void gemm_kernel(const _Float16* __restrict__ A,
                                                   const _Float16* __restrict__ Bm,
                                                   _Float16* __restrict__ C,
                                                   float* __restrict__ sums,
                                                   float* __restrict__ sumsq) {
    __shared__ alignas(16) _Float16 As[2][128 * 32];   // 2 x 8 KB
    __shared__ alignas(16) _Float16 Bs[2][128 * 32];   // 2 x 8 KB
    const int id = blockIdx.x;                 // 0..4095
    const int g  = id >> 5;                    // 128 groups
    const int r  = id & 31;
    const int h  = g >> 4;                     // 8
    const int q  = r & 7;
    const int s  = r >> 3;
    const int mb = ((g & 15) * 8 + (q & 3) * 2 + (s & 1)) * 128;
    const int nb = ((q >> 2) * 2 + (s >> 1)) * 128;

    const int t    = threadIdx.x;
    const int lane = t & 63;
    const int w    = t >> 6;
    const int wm   = (w >> 1) * 64;
    const int wn   = (w & 1) * 64;
    const int quad = lane >> 4;
    const int l16  = lane & 15;

    // staging: thread t fills LDS slot (row=t>>2, s=t&3); loads global chunk
    // kc = (s - (row>>1)) & 3  (row>>1 == t>>3; same for the +64-row half).
    const int kc = ((t & 3) - ((t >> 3) & 3)) & 3;
    const _Float16* Ap = A + (size_t)(mb + (t >> 2)) * Ee + kc * 8;
    const _Float16* Bp = Bm + (size_t)h * Ee * Ee + (size_t)(nb + (t >> 2)) * Ee + kc * 8;

    f32x4 acc[4][4] = {};

    // prologue: stage k0=0 into buf 0
    async_ld16(&As[0][t * 8],        Ap);
    async_ld16(&As[0][2048 + t * 8], Ap + 64 * Ee);
    async_ld16(&Bs[0][t * 8],        Bp);
    async_ld16(&Bs[0][2048 + t * 8], Bp + 64 * Ee);

    // reader slot offset: chunk `quad` of row R lives at slot (quad+(R>>1))&3;
    // R = wm+mt*16+l16 -> (R>>1)&3 == (l16>>1)&3 (wm/2, mt*8 are 0 mod 4).
    const int so = ((quad + (l16 >> 1)) & 3) * 8;

    int buf = 0;
    for (int k0 = 0; k0 < Ee; k0 += 32) {
        __syncthreads();   // drains loads for `buf`; also closes reads of buf^1
        if (k0 + 32 < Ee) {
            int nb2 = buf ^ 1;
            async_ld16(&As[nb2][t * 8],        Ap + k0 + 32);
            async_ld16(&As[nb2][2048 + t * 8], Ap + 64 * Ee + k0 + 32);
            async_ld16(&Bs[nb2][t * 8],        Bp + k0 + 32);
            async_ld16(&Bs[nb2][2048 + t * 8], Bp + 64 * Ee + k0 + 32);
        }
        f16x8 a8[4], b8[4];
#pragma unroll
        for (int mt = 0; mt < 4; ++mt)
            a8[mt] = *(const f16x8*)(&As[buf][(wm + mt * 16 + l16) * 32 + so]);
#pragma unroll
        for (int nt = 0; nt < 4; ++nt)
            b8[nt] = *(const f16x8*)(&Bs[buf][(wn + nt * 16 + l16) * 32 + so]);
#pragma unroll
        for (int mt = 0; mt < 4; ++mt)
#pragma unroll
            for (int nt = 0; nt < 4; ++nt)
                acc[mt][nt] = __builtin_amdgcn_mfma_f32_16x16x32_f16(a8[mt], b8[nt], acc[mt][nt], 0, 0, 0);
        buf ^= 1;
    }

    // BN partial sums: reduce over rows (mt,r) then across quads (lanes xor 16,32)
#pragma unroll
    for (int nt = 0; nt < 4; ++nt) {
        float sv = 0.f, ss = 0.f;
#pragma unroll
        for (int mt = 0; mt < 4; ++mt)
#pragma unroll
            for (int rr = 0; rr < 4; ++rr) { float v = acc[mt][nt][rr]; sv += v; ss += v * v; }
        sv += __shfl_xor(sv, 16, 64); sv += __shfl_xor(sv, 32, 64);
        ss += __shfl_xor(ss, 16, 64); ss += __shfl_xor(ss, 32, 64);
        if (quad == 0) {
            int col = nb + wn + nt * 16 + l16;
            atomicAdd(&sums[h * Ee + col], sv);
            atomicAdd(&sumsq[h * Ee + col], ss);
        }
    }

    // store C (f16): C/D layout col=lane&15, row=quad*4+reg
    _Float16* Cp = C + (size_t)h * Nn * Ee;
#pragma unroll
    for (int mt = 0; mt < 4; ++mt)
#pragma unroll
        for (int rr = 0; rr < 4; ++rr) {
            int row = mb + wm + mt * 16 + quad * 4 + rr;
            size_t off = (size_t)row * Ee + nb + wn + l16;
#pragma unroll
            for (int nt = 0; nt < 4; ++nt)
                Cp[off + nt * 16] = (_Float16)acc[mt][nt][rr];
        }
}

// ---------------- K2: finalize BN stats into affine coefs -----------------------
__global__ __launch_bounds__(256) void stats_kernel(const float* __restrict__ sums,
                                                    const float* __restrict__ sumsq,
                                                    const float* __restrict__ bnw,
                                                    const float* __restrict__ bnb,
                                                    float* __restrict__ cA,
                                                    float* __restrict__ cB) {
    int i = blockIdx.x * 256 + threadIdx.x;    // 0..4095
    float mean = sums[i] * (1.0f / Nn);
    float var  = sumsq[i] * (1.0f / Nn) - mean * mean;
    float inv  = rsqrtf(var + BN_EPS_);
    float a    = bnw[i] * inv;
    cA[i] = a;
    cB[i] = bnb[i] - mean * a;
}

// ---------------- K3: per-row head scan: sparsemax (Michelot) -------------------
// 256 threads = 4 waves, each wave owns one row n. Support count via
// __ballot + __popcll (SALU, wave-uniform) -> one DPP chain per iteration.
__global__ __launch_bounds__(256) void rows_kernel(const float* __restrict__ x,
                                                   const _Float16* __restrict__ lg,
                                                   const float* __restrict__ cA,
                                                   const float* __restrict__ cB,
                                                   float* __restrict__ out) {
    const int n    = blockIdx.x * 4 + (threadIdx.x >> 6);
    const int lane = threadIdx.x & 63;
    const int e0   = lane * 4;                 // first chunk; second at +256
    const int bb   = n >> 9;                   // n / Tt
    const int tt   = n & 511;                  // n % Tt

    float xr[8], prior[8];
    {
        const float* xp = x + (size_t)n * Ee;
        float4 x0 = *(const float4*)(xp + e0);
        float4 x1 = *(const float4*)(xp + 256 + e0);
        xr[0]=x0.x; xr[1]=x0.y; xr[2]=x0.z; xr[3]=x0.w;
        xr[4]=x1.x; xr[5]=x1.y; xr[6]=x1.z; xr[7]=x1.w;
    }
#pragma unroll
    for (int j = 0; j < 8; ++j) prior[j] = 1.0f;

    float* omx = out;                               // (H,B,T,E) flat = (H,N,E)
    float* omk = out + (size_t)Hh * Nn * Ee;        // (B,H,T,E)

    const _Float16* lrow = lg + (size_t)n * Ee;
    f16x4 l0 = *(const f16x4*)(lrow + e0);
    f16x4 l1 = *(const f16x4*)(lrow + 256 + e0);

#pragma unroll 1
    for (int h = 0; h < Hh; ++h) {
        // depth-1 prefetch of next head's logits (independent of prior chain)
        f16x4 p0 = l0, p1 = l1;
        if (h + 1 < Hh) {
            const _Float16* lnx = lrow + (size_t)(h + 1) * Nn * Ee;
            p0 = *(const f16x4*)(lnx + e0);
            p1 = *(const f16x4*)(lnx + 256 + e0);
        }
        float z[8];
        {
            const float* ap = cA + h * Ee + e0;
            const float* bp = cB + h * Ee + e0;
            float4 a0 = *(const float4*)(ap);
            float4 b0 = *(const float4*)(bp);
            float4 a1 = *(const float4*)(ap + 256);
            float4 b1 = *(const float4*)(bp + 256);
            z[0] = ((float)l0[0] * a0.x + b0.x) * prior[0];
            z[1] = ((float)l0[1] * a0.y + b0.y) * prior[1];
            z[2] = ((float)l0[2] * a0.z + b0.z) * prior[2];
            z[3] = ((float)l0[3] * a0.w + b0.w) * prior[3];
            z[4] = ((float)l1[0] * a1.x + b1.x) * prior[4];
            z[5] = ((float)l1[1] * a1.y + b1.y) * prior[5];
            z[6] = ((float)l1[2] * a1.z + b1.z) * prior[6];
            z[7] = ((float)l1[3] * a1.w + b1.w) * prior[7];
        }

        // Michelot (exact sparsemax threshold). Sum via DPP; count via ballot.
        float sl = 0.f;
#pragma unroll
        for (int j = 0; j < 8; ++j) sl += z[j];
        float tau = (dpp_sum64(sl) - 1.0f) * (1.0f / 512.0f);
        int cprev = 512;
#pragma unroll 1
        for (int it = 0; it < 64; ++it) {
            float s2 = 0.f;
            int cnt = 0;
#pragma unroll
            for (int j = 0; j < 8; ++j) {
                bool p = z[j] > tau;
                s2 += p ? z[j] : 0.0f;
                cnt += (int)__popcll(__ballot(p));
            }
            float S = dpp_sum64(s2);
            if (cnt == cprev) break;
            cprev = cnt;
            tau = (S - 1.0f) / (float)cnt;
        }

        size_t oxoff = ((size_t)h * Nn + n) * Ee + e0;
        size_t okoff = (((size_t)bb * Hh + h) * Tt + tt) * Ee + e0;
        f32x4 vx, vm;
#pragma unroll
        for (int j = 0; j < 4; ++j) {
            float m = fmaxf(z[j] - tau, 0.0f);
            prior[j] *= fmaxf(GAMMA_ - m, 0.0f);
            vm[j] = m; vx[j] = xr[j] * m;
        }
        __builtin_nontemporal_store(vx, (f32x4*)(omx + oxoff));
        __builtin_nontemporal_store(vm, (f32x4*)(omk + okoff));
#pragma unroll
        for (int j = 0; j < 4; ++j) {
            float m = fmaxf(z[4 + j] - tau, 0.0f);
            prior[4 + j] *= fmaxf(GAMMA_ - m, 0.0f);
            vm[j] = m; vx[j] = xr[4 + j] * m;
        }
        __builtin_nontemporal_store(vx, (f32x4*)(omx + oxoff + 256));
        __builtin_nontemporal_store(vm, (f32x4*)(omk + okoff + 256));
        l0 = p0; l1 = p1;
    }
}

extern "C" void kernel_launch(void* const* d_in, const int* in_sizes, int n_in,
                              void* d_out, int out_size, void* d_ws, size_t ws_size,
                              hipStream_t stream) {
    const float* x   = (const float*)d_in[0];
    const float* W   = (const float*)d_in[1];
    const float* bnw = (const float*)d_in[2];
    const float* bnb = (const float*)d_in[3];
    float* out = (float*)d_out;

    uint8_t* ws = (uint8_t*)d_ws;
    _Float16* xh = (_Float16*)(ws);                    // 16,777,216 B
    _Float16* wh = (_Float16*)(ws + 16777216);         //  4,194,304 B
    _Float16* lg = (_Float16*)(ws + 20971520);         // 134,217,728 B
    float* sums  = (float*)(ws + 155189248);           // 16,384 B
    float* sumsq = (float*)(ws + 155205632);           // 16,384 B
    float* cA    = (float*)(ws + 155222016);           // 16,384 B
    float* cB    = (float*)(ws + 155238400);           // 16,384 B (total ~148 MB)

    hipMemsetAsync(sums, 0, 2 * 4096 * sizeof(float), stream);  // sums+sumsq contiguous

    cvt_kernel<<<10240, 256, 0, stream>>>(x, W, xh, wh);
    gemm_kernel<<<4096, 256, 0, stream>>>(xh, wh, lg, sums, sumsq);
    stats_kernel<<<16, 256, 0, stream>>>(sums, sumsq, bnw, bnb, cA, cB);
    rows_kernel<<<4096, 256, 0, stream>>>(x, lg, cA, cB, out);
}

// Round 7
// 656.196 us; speedup vs baseline: 1.0638x; 1.0238x over previous
//
#include <hip/hip_runtime.h>
#include <stdint.h>

#define Hh 8
#define Bb 32
#define Tt 512
#define Ee 512
#define Nn 16384            // Bb*Tt
#define GAMMA_ 1.5f
#define BN_EPS_ 1e-5f

typedef _Float16 f16x4 __attribute__((ext_vector_type(4)));
typedef _Float16 f16x8 __attribute__((ext_vector_type(8)));
typedef float    f32x4 __attribute__((ext_vector_type(4)));

__device__ __forceinline__ void async_ld16(void* lds, const void* g) {
    __builtin_amdgcn_global_load_lds(
        (const __attribute__((address_space(1))) void*)g,
        (__attribute__((address_space(3))) void*)lds, 16, 0, 0);
}

// Full-wave (64-lane) f32 sum via DPP (pure VALU, no DS pipe).
__device__ __forceinline__ float dpp_sum64(float v) {
    int t;
    t = __builtin_amdgcn_update_dpp(0, __float_as_int(v), 0x111, 0xf, 0xf, true);
    v += __int_as_float(t);
    t = __builtin_amdgcn_update_dpp(0, __float_as_int(v), 0x112, 0xf, 0xf, true);
    v += __int_as_float(t);
    t = __builtin_amdgcn_update_dpp(0, __float_as_int(v), 0x114, 0xf, 0xf, true);
    v += __int_as_float(t);
    t = __builtin_amdgcn_update_dpp(0, __float_as_int(v), 0x118, 0xf, 0xf, true);
    v += __int_as_float(t);
    t = __builtin_amdgcn_update_dpp(0, __float_as_int(v), 0x142, 0xf, 0xf, true);
    v += __int_as_float(t);
    t = __builtin_amdgcn_update_dpp(0, __float_as_int(v), 0x143, 0xf, 0xf, true);
    v += __int_as_float(t);
    return __int_as_float(__builtin_amdgcn_readlane(__float_as_int(v), 63));
}

// ---------------- K0: fp32 -> f16 convert (x then W, contiguous) ----------------
__global__ __launch_bounds__(256) void cvt_kernel(const float* __restrict__ x,
                                                  const float* __restrict__ W,
                                                  _Float16* __restrict__ xh,
                                                  _Float16* __restrict__ wh) {
    const int NX = Bb * Tt * Ee;               // 8388608, divisible by 4
    int i = (blockIdx.x * 256 + threadIdx.x) * 4;
    if (i < NX) {
        float4 v = *(const float4*)(x + i);
        f16x4 o = {(_Float16)v.x, (_Float16)v.y, (_Float16)v.z, (_Float16)v.w};
        *(f16x4*)(xh + i) = o;
    } else {
        int j = i - NX;                        // 0 .. 2097151
        float4 v = *(const float4*)(W + j);
        f16x4 o = {(_Float16)v.x, (_Float16)v.y, (_Float16)v.z, (_Float16)v.w};
        *(f16x4*)(wh + j) = o;
    }
}

// ---------------- K1: batched NT GEMM, 256x256 tiles, f16 MFMA, dbuf LDS --------
// 512 threads = 8 waves (2 row x 4 col), each wave 128x64. Staging traffic
// halves vs 128-tile (537 MB total). K-chunk rotate swizzle keeps ds_read_b128
// at the 2-lanes/bank minimum.
__global__ __launch_bounds__(512, 2) void gemm_kernel(const _Float16* __restrict__ A,
                                                      const _Float16* __restrict__ Bm,
                                                      _Float16* __restrict__ C,
                                                      float* __restrict__ sums,
                                                      float* __restrict__ sumsq) {
    __shared__ alignas(16) _Float16 As[2][256 * 32];   // 2 x 16 KB
    __shared__ alignas(16) _Float16 Bs[2][256 * 32];   // 2 x 16 KB
    const int id  = blockIdx.x;                // 0..1023
    const int h   = id >> 7;
    const int rem = id & 127;
    const int mb  = (rem >> 1) * 256;          // 64 row-blocks
    const int nb  = (rem & 1) * 256;           // 2 col-blocks

    const int t    = threadIdx.x;              // 0..511
    const int lane = t & 63;
    const int w    = t >> 6;                   // 0..7
    const int wrow = (w >> 2) * 128;           // 0,128
    const int wcol = (w & 3) * 64;             // 0,64,128,192
    const int quad = lane >> 4;
    const int l16  = lane & 15;

    // staging: thread t fills LDS chunks t and t+512 (rows t>>2 and 128+(t>>2),
    // slot t&3). Global k-chunk kc = (slot - (row>>1)) & 3; identical for both
    // chunks since +128 rows ≡ 0 mod 4 after >>1.
    const int kc = ((t & 3) - ((t >> 3) & 3)) & 3;
    const _Float16* Ap = A + (size_t)(mb + (t >> 2)) * Ee + kc * 8;
    const _Float16* Bp = Bm + (size_t)h * Ee * Ee + (size_t)(nb + (t >> 2)) * Ee + kc * 8;

    f32x4 acc[8][4] = {};

    // prologue: stage k0=0 into buf 0
    async_ld16(&As[0][t * 8],        Ap);
    async_ld16(&As[0][4096 + t * 8], Ap + 128 * Ee);
    async_ld16(&Bs[0][t * 8],        Bp);
    async_ld16(&Bs[0][4096 + t * 8], Bp + 128 * Ee);

    // reader slot: chunk `quad` of row R lives at slot (quad+(R>>1))&3;
    // (R>>1)&3 == (l16>>1)&3 for all wrow/wcol/mt/nt used here.
    const int so = ((quad + (l16 >> 1)) & 3) * 8;

    int buf = 0;
    for (int k0 = 0; k0 < Ee; k0 += 32) {
        __syncthreads();   // drains loads for `buf`; also closes reads of buf^1
        if (k0 + 32 < Ee) {
            int nx = buf ^ 1;
            async_ld16(&As[nx][t * 8],        Ap + k0 + 32);
            async_ld16(&As[nx][4096 + t * 8], Ap + 128 * Ee + k0 + 32);
            async_ld16(&Bs[nx][t * 8],        Bp + k0 + 32);
            async_ld16(&Bs[nx][4096 + t * 8], Bp + 128 * Ee + k0 + 32);
        }
        f16x8 b8[4];
#pragma unroll
        for (int nt = 0; nt < 4; ++nt)
            b8[nt] = *(const f16x8*)(&Bs[buf][(wcol + nt * 16 + l16) * 32 + so]);
#pragma unroll
        for (int mt = 0; mt < 8; ++mt) {
            f16x8 a8 = *(const f16x8*)(&As[buf][(wrow + mt * 16 + l16) * 32 + so]);
#pragma unroll
            for (int nt = 0; nt < 4; ++nt)
                acc[mt][nt] = __builtin_amdgcn_mfma_f32_16x16x32_f16(a8, b8[nt], acc[mt][nt], 0, 0, 0);
        }
        buf ^= 1;
    }

    // BN partial sums: reduce over rows (mt,r) then across quads (lanes xor 16,32)
#pragma unroll
    for (int nt = 0; nt < 4; ++nt) {
        float sv = 0.f, ss = 0.f;
#pragma unroll
        for (int mt = 0; mt < 8; ++mt)
#pragma unroll
            for (int rr = 0; rr < 4; ++rr) { float v = acc[mt][nt][rr]; sv += v; ss += v * v; }
        sv += __shfl_xor(sv, 16, 64); sv += __shfl_xor(sv, 32, 64);
        ss += __shfl_xor(ss, 16, 64); ss += __shfl_xor(ss, 32, 64);
        if (quad == 0) {
            int col = nb + wcol + nt * 16 + l16;
            atomicAdd(&sums[h * Ee + col], sv);
            atomicAdd(&sumsq[h * Ee + col], ss);
        }
    }

    // store C (f16): C/D layout col=lane&15, row=quad*4+reg
    _Float16* Cp = C + (size_t)h * Nn * Ee;
#pragma unroll
    for (int mt = 0; mt < 8; ++mt)
#pragma unroll
        for (int rr = 0; rr < 4; ++rr) {
            int row = mb + wrow + mt * 16 + quad * 4 + rr;
            size_t off = (size_t)row * Ee + nb + wcol + l16;
#pragma unroll
            for (int nt = 0; nt < 4; ++nt)
                Cp[off + nt * 16] = (_Float16)acc[mt][nt][rr];
        }
}

// ---------------- K2: finalize BN stats into affine coefs -----------------------
__global__ __launch_bounds__(256) void stats_kernel(const float* __restrict__ sums,
                                                    const float* __restrict__ sumsq,
                                                    const float* __restrict__ bnw,
                                                    const float* __restrict__ bnb,
                                                    float* __restrict__ cA,
                                                    float* __restrict__ cB) {
    int i = blockIdx.x * 256 + threadIdx.x;    // 0..4095
    float mean = sums[i] * (1.0f / Nn);
    float var  = sumsq[i] * (1.0f / Nn) - mean * mean;
    float inv  = rsqrtf(var + BN_EPS_);
    float a    = bnw[i] * inv;
    cA[i] = a;
    cB[i] = bnb[i] - mean * a;
}

// ---------------- K3: per-row head scan: sparsemax (Michelot) -------------------
// 256 threads = 4 waves, each wave owns one row n. Support count via
// __ballot + __popcll (SALU, wave-uniform) -> one DPP chain per iteration.
__global__ __launch_bounds__(256) void rows_kernel(const float* __restrict__ x,
                                                   const _Float16* __restrict__ lg,
                                                   const float* __restrict__ cA,
                                                   const float* __restrict__ cB,
                                                   float* __restrict__ out) {
    const int n    = blockIdx.x * 4 + (threadIdx.x >> 6);
    const int lane = threadIdx.x & 63;
    const int e0   = lane * 4;                 // first chunk; second at +256
    const int bb   = n >> 9;                   // n / Tt
    const int tt   = n & 511;                  // n % Tt

    float xr[8], prior[8];
    {
        const float* xp = x + (size_t)n * Ee;
        float4 x0 = *(const float4*)(xp + e0);
        float4 x1 = *(const float4*)(xp + 256 + e0);
        xr[0]=x0.x; xr[1]=x0.y; xr[2]=x0.z; xr[3]=x0.w;
        xr[4]=x1.x; xr[5]=x1.y; xr[6]=x1.z; xr[7]=x1.w;
    }
#pragma unroll
    for (int j = 0; j < 8; ++j) prior[j] = 1.0f;

    float* omx = out;                               // (H,B,T,E) flat = (H,N,E)
    float* omk = out + (size_t)Hh * Nn * Ee;        // (B,H,T,E)

    const _Float16* lrow = lg + (size_t)n * Ee;
    f16x4 l0 = *(const f16x4*)(lrow + e0);
    f16x4 l1 = *(const f16x4*)(lrow + 256 + e0);

#pragma unroll 1
    for (int h = 0; h < Hh; ++h) {
        // depth-1 prefetch of next head's logits (independent of prior chain)
        f16x4 p0 = l0, p1 = l1;
        if (h + 1 < Hh) {
            const _Float16* lnx = lrow + (size_t)(h + 1) * Nn * Ee;
            p0 = *(const f16x4*)(lnx + e0);
            p1 = *(const f16x4*)(lnx + 256 + e0);
        }
        float z[8];
        {
            const float* ap = cA + h * Ee + e0;
            const float* bp = cB + h * Ee + e0;
            float4 a0 = *(const float4*)(ap);
            float4 b0 = *(const float4*)(bp);
            float4 a1 = *(const float4*)(ap + 256);
            float4 b1 = *(const float4*)(bp + 256);
            z[0] = ((float)l0[0] * a0.x + b0.x) * prior[0];
            z[1] = ((float)l0[1] * a0.y + b0.y) * prior[1];
            z[2] = ((float)l0[2] * a0.z + b0.z) * prior[2];
            z[3] = ((float)l0[3] * a0.w + b0.w) * prior[3];
            z[4] = ((float)l1[0] * a1.x + b1.x) * prior[4];
            z[5] = ((float)l1[1] * a1.y + b1.y) * prior[5];
            z[6] = ((float)l1[2] * a1.z + b1.z) * prior[6];
            z[7] = ((float)l1[3] * a1.w + b1.w) * prior[7];
        }

        // Michelot (exact sparsemax threshold). Sum via DPP; count via ballot.
        float sl = 0.f;
#pragma unroll
        for (int j = 0; j < 8; ++j) sl += z[j];
        float tau = (dpp_sum64(sl) - 1.0f) * (1.0f / 512.0f);
        int cprev = 512;
#pragma unroll 1
        for (int it = 0; it < 64; ++it) {
            float s2 = 0.f;
            int cnt = 0;
#pragma unroll
            for (int j = 0; j < 8; ++j) {
                bool p = z[j] > tau;
                s2 += p ? z[j] : 0.0f;
                cnt += (int)__popcll(__ballot(p));
            }
            float S = dpp_sum64(s2);
            if (cnt == cprev) break;
            cprev = cnt;
            tau = (S - 1.0f) / (float)cnt;
        }

        size_t oxoff = ((size_t)h * Nn + n) * Ee + e0;
        size_t okoff = (((size_t)bb * Hh + h) * Tt + tt) * Ee + e0;
        f32x4 vx, vm;
#pragma unroll
        for (int j = 0; j < 4; ++j) {
            float m = fmaxf(z[j] - tau, 0.0f);
            prior[j] *= fmaxf(GAMMA_ - m, 0.0f);
            vm[j] = m; vx[j] = xr[j] * m;
        }
        __builtin_nontemporal_store(vx, (f32x4*)(omx + oxoff));
        __builtin_nontemporal_store(vm, (f32x4*)(omk + okoff));
#pragma unroll
        for (int j = 0; j < 4; ++j) {
            float m = fmaxf(z[4 + j] - tau, 0.0f);
            prior[4 + j] *= fmaxf(GAMMA_ - m, 0.0f);
            vm[j] = m; vx[j] = xr[4 + j] * m;
        }
        __builtin_nontemporal_store(vx, (f32x4*)(omx + oxoff + 256));
        __builtin_nontemporal_store(vm, (f32x4*)(omk + okoff + 256));
        l0 = p0; l1 = p1;
    }
}

extern "C" void kernel_launch(void* const* d_in, const int* in_sizes, int n_in,
                              void* d_out, int out_size, void* d_ws, size_t ws_size,
                              hipStream_t stream) {
    const float* x   = (const float*)d_in[0];
    const float* W   = (const float*)d_in[1];
    const float* bnw = (const float*)d_in[2];
    const float* bnb = (const float*)d_in[3];
    float* out = (float*)d_out;

    uint8_t* ws = (uint8_t*)d_ws;
    _Float16* xh = (_Float16*)(ws);                    // 16,777,216 B
    _Float16* wh = (_Float16*)(ws + 16777216);         //  4,194,304 B
    _Float16* lg = (_Float16*)(ws + 20971520);         // 134,217,728 B
    float* sums  = (float*)(ws + 155189248);           // 16,384 B
    float* sumsq = (float*)(ws + 155205632);           // 16,384 B
    float* cA    = (float*)(ws + 155222016);           // 16,384 B
    float* cB    = (float*)(ws + 155238400);           // 16,384 B (total ~148 MB)

    hipMemsetAsync(sums, 0, 2 * 4096 * sizeof(float), stream);  // sums+sumsq contiguous

    cvt_kernel<<<10240, 256, 0, stream>>>(x, W, xh, wh);
    gemm_kernel<<<1024, 512, 0, stream>>>(xh, wh, lg, sums, sumsq);
    stats_kernel<<<16, 256, 0, stream>>>(sums, sumsq, bnw, bnb, cA, cB);
    rows_kernel<<<4096, 256, 0, stream>>>(x, lg, cA, cB, out);
}